// Round 10
// baseline (150.004 us; speedup 1.0000x reference)
//
#include <hip/hip_runtime.h>
#include <hip/hip_bf16.h>
#include <type_traits>

// ---------------- problem constants ----------------
static constexpr int T    = 4096;
static constexpr int F    = 256;
static constexpr int M    = 2 * T;        // 8192 rows
static constexpr int HPS  = 4;
static constexpr int CTX0 = 31, CTX1 = 61;

typedef short bf16x8 __attribute__((ext_vector_type(8)));
typedef float f32x4  __attribute__((ext_vector_type(4)));

__device__ __forceinline__ ushort f2bf(float f) {
    union { float f; uint u; } v; v.f = f;
    uint u = v.u;
    return (ushort)((u + 0x7fffu + ((u >> 16) & 1u)) >> 16);   // RNE
}
__device__ __forceinline__ float asf(uint u) {
    union { uint u; float f; } v; v.u = u; return v.f;
}
__device__ __forceinline__ float bf2f(ushort u) { return asf(((uint)u) << 16); }

// ---------------- packed transposed weights in ws ----------------
// w1t[512][256] | w2blk[384][512] (block-diag) | w3t[512][256] | wot[256][256]
static constexpr size_t W1T_OFF  = 0;
static constexpr size_t W2B_OFF  = W1T_OFF + (size_t)512 * 256;
static constexpr size_t W3T_OFF  = W2B_OFF + (size_t)384 * 512;
static constexpr size_t WOT_OFF  = W3T_OFF + (size_t)512 * 256;
static constexpr size_t WT_ELEMS = WOT_OFF + (size_t)256 * 256;

struct WArgs {
    const float* w1_0; const float* w1_1;
    const float* w2_0; const float* w2_1;
    const float* w3_0; const float* w3_1;
    const float* wo;
    ushort* wt;
};

// One 64x64 dst tile per block; coalesced fp32 read -> LDS -> transposed bf16 write.
__global__ __launch_bounds__(256) void wprep_kernel(WArgs a) {
    __shared__ float tb[64][72];
    const int tid = threadIdx.x;
    const int blk = blockIdx.x;

    const float* src = nullptr;
    ushort* dst; int dstLD, k0, nbase; bool isw2 = false;

    if (blk < 64) {
        int sec = blk >> 4;                   // 0 W1_0, 1 W1_1, 2 W3_0, 3 W3_1
        int tt = blk & 15, kt = tt >> 2, nt = tt & 3;
        k0 = kt * 64;
        src = (sec == 0) ? a.w1_0 : (sec == 1) ? a.w1_1 : (sec == 2) ? a.w3_0 : a.w3_1;
        dst = a.wt + ((sec < 2) ? W1T_OFF : W3T_OFF);
        nbase = (sec & 1) * 256 + nt * 64;
        dstLD = 256;
    } else if (blk < 80) {
        int tt = blk - 64, kt = tt >> 2, nt = tt & 3;
        k0 = kt * 64; src = a.wo; dst = a.wt + WOT_OFF; nbase = nt * 64; dstLD = 256;
    } else {
        int tt = blk - 80;                    // 6 n-tiles x 8 k-tiles
        int nt = tt >> 3, kt = tt & 7;
        k0 = kt * 64; nbase = nt * 64; dst = a.wt + W2B_OFF; dstLD = 512; isw2 = true;
    }

    {
        int kk = tid >> 2;
        int c4 = (tid & 3) * 16;
        if (!isw2) {
            int ncol0 = (blk < 64) ? (nbase & 255) : nbase;
            const float* sp = src + (size_t)(k0 + kk) * 256 + ncol0 + c4;
#pragma unroll
            for (int ii = 0; ii < 4; ii++) {
                float4 v = *reinterpret_cast<const float4*>(sp + ii * 4);
                tb[kk][c4 + ii * 4 + 0] = v.x; tb[kk][c4 + ii * 4 + 1] = v.y;
                tb[kk][c4 + ii * 4 + 2] = v.z; tb[kk][c4 + ii * 4 + 3] = v.w;
            }
        } else {
            int k = k0 + kk;
#pragma unroll 4
            for (int ii = 0; ii < 16; ii++) {
                int n = nbase + c4 + ii;
                float v = 0.f;
                if (n < 124) { if (k < 256) v = a.w2_0[(size_t)k * 124 + n]; }
                else if (n < 368) { if (k >= 256) v = a.w2_1[(size_t)(k - 256) * 244 + (n - 124)]; }
                tb[kk][c4 + ii] = v;
            }
        }
    }
    __syncthreads();

#pragma unroll
    for (int it = 0; it < 2; it++) {
        int slot = it * 256 + tid;
        int n = slot >> 3, ch = slot & 7;
        ushort o[8];
#pragma unroll
        for (int j = 0; j < 8; j++) o[j] = f2bf(tb[ch * 8 + j][n]);
        *reinterpret_cast<bf16x8*>(dst + (size_t)(nbase + n) * dstLD + k0 + ch * 8) =
            *reinterpret_cast<bf16x8*>(o);
    }
}

// ---------------- 128x128 double-buffered bf16 MFMA GEMM (paired) ----------------
struct GemmArgs {
    const void* A0; const void* A1;
    const ushort* B0; const ushort* B1;
    void* C0; void* C1;
    int lda, N, ncb, relu0, relu1;
};

template <int KTOT, typename OutT>
__global__ __launch_bounds__(256, 2) void gemm128_kernel(GemmArgs a) {
    __shared__ ushort Al[2][128][64];
    __shared__ ushort Bl[2][128][64];

    const int tid = threadIdx.x;
    int lin = blockIdx.x;
    int half = gridDim.x >> 1;
    int sel = lin >= half;
    lin -= sel * half;
    const int qq  = half >> 3;
    const int swz = (lin & 7) * qq + (lin >> 3);
    const int cb  = swz % a.ncb;
    const int rb  = swz / a.ncb;
    const int m0  = rb * 128;
    const int n0  = cb * 128;

    const float*  Av  = (const float*)(sel ? a.A1 : a.A0);
    const ushort* Bt  = sel ? a.B1 : a.B0;
    OutT*         C   = (OutT*)(sel ? a.C1 : a.C0);
    const bool    relu = sel ? (a.relu1 != 0) : (a.relu0 != 0);
    const int     lda = a.lda, N = a.N;

    const int wave = tid >> 6, lane = tid & 63;
    const int wr = wave >> 1, wc = wave & 1;
    const int l15 = lane & 15, l4 = lane >> 4;
    const int srow = tid >> 3;
    const int sch  = tid & 7;

    float4 pAf[4][2];
    bf16x8 pB[4];

    auto loadRegs = [&](int s) {
        const int k0 = s * 64;
#pragma unroll
        for (int it = 0; it < 4; it++) {
            int row = it * 32 + srow;
            const float* ap = Av + (size_t)(m0 + row) * lda + k0 + sch * 8;
            pAf[it][0] = *reinterpret_cast<const float4*>(ap);
            pAf[it][1] = *reinterpret_cast<const float4*>(ap + 4);
            pB[it] = *reinterpret_cast<const bf16x8*>(
                Bt + (size_t)(n0 + row) * KTOT + k0 + sch * 8);
        }
    };
    auto writeLds = [&](int buf) {
#pragma unroll
        for (int it = 0; it < 4; it++) {
            int row = it * 32 + srow;
            int c8  = (sch ^ (row & 7)) * 8;
            ushort o[8] = { f2bf(pAf[it][0].x), f2bf(pAf[it][0].y),
                            f2bf(pAf[it][0].z), f2bf(pAf[it][0].w),
                            f2bf(pAf[it][1].x), f2bf(pAf[it][1].y),
                            f2bf(pAf[it][1].z), f2bf(pAf[it][1].w) };
            *reinterpret_cast<bf16x8*>(&Al[buf][row][c8]) = *reinterpret_cast<bf16x8*>(o);
            *reinterpret_cast<bf16x8*>(&Bl[buf][row][c8]) = pB[it];
        }
    };

    f32x4 acc[4][4] = {};

    loadRegs(0);
    writeLds(0);
    constexpr int NST = KTOT / 64;
#pragma unroll
    for (int s = 0; s < NST; s++) {
        if (s + 1 < NST) loadRegs(s + 1);
        __syncthreads();
        if (s + 1 < NST) writeLds((s + 1) & 1);
        const int buf = s & 1;
#pragma unroll
        for (int ks = 0; ks < 2; ks++) {
            bf16x8 af[4], bv[4];
#pragma unroll
            for (int i = 0; i < 4; i++) {
                int row = wr * 64 + i * 16 + l15;
                int ch  = (ks * 4 + l4) ^ (row & 7);
                af[i] = *reinterpret_cast<const bf16x8*>(&Al[buf][row][ch * 8]);
            }
#pragma unroll
            for (int j = 0; j < 4; j++) {
                int row = wc * 64 + j * 16 + l15;
                int ch  = (ks * 4 + l4) ^ (row & 7);
                bv[j] = *reinterpret_cast<const bf16x8*>(&Bl[buf][row][ch * 8]);
            }
#pragma unroll
            for (int i = 0; i < 4; i++)
#pragma unroll
                for (int j = 0; j < 4; j++)
                    acc[i][j] = __builtin_amdgcn_mfma_f32_16x16x32_bf16(af[i], bv[j], acc[i][j], 0, 0, 0);
        }
    }

#pragma unroll
    for (int i = 0; i < 4; i++)
#pragma unroll
        for (int j = 0; j < 4; j++) {
            int col = n0 + wc * 64 + j * 16 + l15;
#pragma unroll
            for (int r = 0; r < 4; r++) {
                int row = m0 + wr * 64 + i * 16 + l4 * 4 + r;
                float v = acc[i][j][r];
                if (relu) v = fmaxf(v, 0.0f);
                C[(size_t)row * N + col] = f2bf(v);
            }
        }
}

// ---------------- fused: logits GEMM + softmax + winsum + out GEMM ----------------
// 256 blocks x 256 threads, 32 tokens/block. LDS 124.5 KB -> 1 block/CU.
__global__ __launch_bounds__(256) void fused_kernel(
    const ushort* __restrict__ q01,    // [M][512] bf16
    const ushort* __restrict__ v01,    // [M][512] bf16
    const ushort* __restrict__ w2blk,  // [384][512] bf16 (rows = logits cols)
    const ushort* __restrict__ wot,    // [256][256] bf16 (rows = out cols)
    const float*  __restrict__ scale_w,
    float*        __restrict__ out)    // [M][256] f32
{
    __shared__ ushort qs[32][512];     // 32 KB (later reused as psum[32][256])
    __shared__ float  lgs[32][372];    // 46.5 KB (368 used)
    __shared__ ushort vl[92][256];     // 46 KB (v0 uses 62 rows, then v1 92)

    const int tid = threadIdx.x;
    const int lin = blockIdx.x;
    const int qq  = gridDim.x >> 3;
    const int swz = (lin & 7) * qq + (lin >> 3);   // XCD-contiguous token blocks
    const int bt0 = swz * 32;
    const int b   = bt0 >> 12;
    const int t0  = bt0 & (T - 1);

    const int wave = tid >> 6, lane = tid & 63;
    const int l15 = lane & 15, l4 = lane >> 4;

    // ---- stage q rows (XOR-swizzled chunks) + v0 window (linear) ----
    for (int i = tid; i < 32 * 64; i += 256) {
        int row = i >> 6, ch = i & 63;
        bf16x8 v = *reinterpret_cast<const bf16x8*>(q01 + (size_t)(bt0 + row) * 512 + ch * 8);
        *reinterpret_cast<bf16x8*>(&qs[row][(ch ^ (row & 7)) * 8]) = v;
    }
    for (int i = tid; i < 62 * 32; i += 256) {
        int row = i >> 5, ch = i & 31;
        int tt = t0 - 15 + row;
        bf16x8 v = {};
        if ((unsigned)tt < (unsigned)T)
            v = *reinterpret_cast<const bf16x8*>(v01 + (size_t)(b * T + tt) * 512 + ch * 8);
        *reinterpret_cast<bf16x8*>(&vl[row][ch * 8]) = v;
    }
    __syncthreads();

    // ---- phase A: lgs[32][368] = qs @ w2blk^T (23 col-tiles over 4 waves) ----
    for (int ct = wave; ct < 23; ct += 4) {
        f32x4 acc0 = {}, acc1 = {};
#pragma unroll
        for (int ks = 0; ks < 16; ks++) {
            int ch = (ks * 4 + l4) ^ (l15 & 7);
            bf16x8 a0 = *reinterpret_cast<const bf16x8*>(&qs[l15][ch * 8]);
            bf16x8 a1 = *reinterpret_cast<const bf16x8*>(&qs[16 + l15][ch * 8]);
            bf16x8 bv = *reinterpret_cast<const bf16x8*>(
                w2blk + (size_t)(ct * 16 + l15) * 512 + ks * 32 + l4 * 8);
            acc0 = __builtin_amdgcn_mfma_f32_16x16x32_bf16(a0, bv, acc0, 0, 0, 0);
            acc1 = __builtin_amdgcn_mfma_f32_16x16x32_bf16(a1, bv, acc1, 0, 0, 0);
        }
#pragma unroll
        for (int r = 0; r < 4; r++) {
            lgs[l4 * 4 + r][ct * 16 + l15]      = acc0[r];
            lgs[16 + l4 * 4 + r][ct * 16 + l15] = acc1[r];
        }
    }
    __syncthreads();

    // ---- scale-weight softmax ----
    float s0 = scale_w[0], s1 = scale_w[1];
    float mxs = fmaxf(s0, s1);
    float e0 = __expf(s0 - mxs), e1 = __expf(s1 - mxs);
    float sw0 = e0 / (e0 + e1), sw1 = e1 / (e0 + e1);

    // ---- per-(tok,scale,head) softmax, in place, sw folded (256 tasks) ----
    {
        int tok = tid >> 3, j = tid & 7;
        int sc = j >> 2, h = j & 3;
        int ctx = sc ? CTX1 : CTX0;
        float sw = sc ? sw1 : sw0;
        float* lp = &lgs[tok][sc ? 124 + h * CTX1 : h * CTX0];
        float mx = -1e30f;
        for (int c = 0; c < ctx; c++) mx = fmaxf(mx, lp[c]);
        float s = 0.f;
        for (int c = 0; c < ctx; c++) { float e = __expf(lp[c] - mx); lp[c] = e; s += e; }
        float scl = sw / s;
        for (int c = 0; c < ctx; c++) lp[c] *= scl;
    }
    __syncthreads();

    // ---- winsum: thread = (8 tok-groups, 32 feat-groups), acc in regs ----
    const int wgr = tid >> 5;
    const int f0  = (tid & 31) * 8;
    const int h   = f0 >> 6;
    float fa[4][8] = {};

#pragma unroll
    for (int tk = 0; tk < 4; tk++) {
        int tok = tk * 8 + wgr;
        const float* aw = &lgs[tok][h * CTX0];
        for (int c = 0; c < CTX0; c++) {
            float wv = aw[c];
            uint4 u = *reinterpret_cast<const uint4*>(&vl[tok + c][f0]);
            fa[tk][0] += wv * asf(u.x << 16); fa[tk][1] += wv * asf(u.x & 0xffff0000u);
            fa[tk][2] += wv * asf(u.y << 16); fa[tk][3] += wv * asf(u.y & 0xffff0000u);
            fa[tk][4] += wv * asf(u.z << 16); fa[tk][5] += wv * asf(u.z & 0xffff0000u);
            fa[tk][6] += wv * asf(u.w << 16); fa[tk][7] += wv * asf(u.w & 0xffff0000u);
        }
    }
    __syncthreads();

    // ---- swap in v1 window ----
    for (int i = tid; i < 92 * 32; i += 256) {
        int row = i >> 5, ch = i & 31;
        int tt = t0 - 30 + row;
        bf16x8 v = {};
        if ((unsigned)tt < (unsigned)T)
            v = *reinterpret_cast<const bf16x8*>(v01 + (size_t)(b * T + tt) * 512 + 256 + ch * 8);
        *reinterpret_cast<bf16x8*>(&vl[row][ch * 8]) = v;
    }
    __syncthreads();

#pragma unroll
    for (int tk = 0; tk < 4; tk++) {
        int tok = tk * 8 + wgr;
        const float* aw = &lgs[tok][124 + h * CTX1];
        for (int c = 0; c < CTX1; c++) {
            float wv = aw[c];
            uint4 u = *reinterpret_cast<const uint4*>(&vl[tok + c][f0]);
            fa[tk][0] += wv * asf(u.x << 16); fa[tk][1] += wv * asf(u.x & 0xffff0000u);
            fa[tk][2] += wv * asf(u.y << 16); fa[tk][3] += wv * asf(u.y & 0xffff0000u);
            fa[tk][4] += wv * asf(u.z << 16); fa[tk][5] += wv * asf(u.z & 0xffff0000u);
            fa[tk][6] += wv * asf(u.w << 16); fa[tk][7] += wv * asf(u.w & 0xffff0000u);
        }
    }
    __syncthreads();   // qs arena free to reuse now

    // ---- psum (bf16, swizzled) into qs arena ----
    ushort* psumb = &qs[0][0];          // [32][256]
#pragma unroll
    for (int tk = 0; tk < 4; tk++) {
        int tok = tk * 8 + wgr;
        ushort o[8];
#pragma unroll
        for (int j = 0; j < 8; j++) o[j] = f2bf(fa[tk][j]);
        int ch = f0 >> 3;
        *reinterpret_cast<bf16x8*>(psumb + tok * 256 + ((ch ^ (tok & 7)) * 8)) =
            *reinterpret_cast<bf16x8*>(o);
    }
    __syncthreads();

    // ---- phase D: out = psum @ wot^T (16 col-tiles over 4 waves) ----
    for (int ct = wave; ct < 16; ct += 4) {
        f32x4 acc0 = {}, acc1 = {};
#pragma unroll
        for (int ks = 0; ks < 8; ks++) {
            int ch = (ks * 4 + l4) ^ (l15 & 7);
            bf16x8 a0 = *reinterpret_cast<const bf16x8*>(psumb + l15 * 256 + ch * 8);
            bf16x8 a1 = *reinterpret_cast<const bf16x8*>(psumb + (16 + l15) * 256 + ch * 8);
            bf16x8 bv = *reinterpret_cast<const bf16x8*>(
                wot + (size_t)(ct * 16 + l15) * 256 + ks * 32 + l4 * 8);
            acc0 = __builtin_amdgcn_mfma_f32_16x16x32_bf16(a0, bv, acc0, 0, 0, 0);
            acc1 = __builtin_amdgcn_mfma_f32_16x16x32_bf16(a1, bv, acc1, 0, 0, 0);
        }
#pragma unroll
        for (int r = 0; r < 4; r++) {
            out[(size_t)(bt0 + l4 * 4 + r) * 256 + ct * 16 + l15]      = acc0[r];
            out[(size_t)(bt0 + 16 + l4 * 4 + r) * 256 + ct * 16 + l15] = acc1[r];
        }
    }
}

// ---------------- host launcher ----------------
extern "C" void kernel_launch(void* const* d_in, const int* in_sizes, int n_in,
                              void* d_out, int out_size, void* d_ws, size_t ws_size,
                              hipStream_t stream)
{
    const float* Q    = (const float*)d_in[0];
    const float* V    = (const float*)d_in[2];
    const float* W1_0 = (const float*)d_in[3];
    const float* W1_1 = (const float*)d_in[4];
    const float* W2_0 = (const float*)d_in[5];
    const float* W2_1 = (const float*)d_in[6];
    const float* W3_0 = (const float*)d_in[7];
    const float* W3_1 = (const float*)d_in[8];
    const float* SW   = (const float*)d_in[9];
    const float* WO   = (const float*)d_in[10];

    char* pws = (char*)d_ws;
    auto carve = [&](size_t bytes) { char* r = pws; pws += (bytes + 255) & ~255ull; return r; };
    ushort* wt  = (ushort*)carve(WT_ELEMS * 2);           // 1.0 MB
    ushort* q01 = (ushort*)carve((size_t)M * 512 * 2);    // 8.4 MB
    ushort* v01 = (ushort*)carve((size_t)M * 512 * 2);    // 8.4 MB
    (void)ws_size;

    const ushort* w1t   = wt + W1T_OFF;
    const ushort* w2blk = wt + W2B_OFF;
    const ushort* w3t   = wt + W3T_OFF;
    const ushort* wot   = wt + WOT_OFF;

    // 1) weight transpose/pack
    wprep_kernel<<<128, 256, 0, stream>>>(
        WArgs{ W1_0, W1_1, W2_0, W2_1, W3_0, W3_1, WO, wt });

    // 2) paired: q01 = relu(Q @ W1cat), v01 = V @ W3cat
    {
        GemmArgs ga{};
        ga.A0 = Q;  ga.A1 = V;
        ga.B0 = w1t; ga.B1 = w3t;
        ga.C0 = q01; ga.C1 = v01;
        ga.lda = 256; ga.N = 512; ga.ncb = 4; ga.relu0 = 1; ga.relu1 = 0;
        gemm128_kernel<256, ushort><<<512, 256, 0, stream>>>(ga);
    }

    // 3) fused logits + softmax + windowed sums + output projection
    fused_kernel<<<256, 256, 0, stream>>>(q01, v01, w2blk, wot, SW, (float*)d_out);
}